// Round 2
// baseline (2158.403 us; speedup 1.0000x reference)
//
#include <hip/hip_runtime.h>
#include <hip/hip_bf16.h>

namespace {

constexpr int kV = 50000;
constexpr int kD = 128;
constexpr int kB = 512;
constexpr int kT = 256;
constexpr int kU = 256;

typedef __attribute__((ext_vector_type(8))) short  bfrag8;   // 8 x bf16 -> 4 VGPR (MFMA operand)
typedef __attribute__((ext_vector_type(4))) float  facc4;    // MFMA accumulator
typedef __attribute__((ext_vector_type(4))) float  vfloat4;
typedef __attribute__((ext_vector_type(4))) int    vint4;

__device__ __forceinline__ unsigned short f2bf(float f) {
  return __builtin_bit_cast(unsigned short, __float2bfloat16(f));
}
__device__ __forceinline__ float bf2f(unsigned short u) {
  unsigned int i = ((unsigned int)u) << 16;
  return __builtin_bit_cast(float, i);
}
__device__ __forceinline__ float bflo(unsigned v) {          // bf16 in low half
  return __builtin_bit_cast(float, v << 16);
}
__device__ __forceinline__ float bfhi(unsigned v) {          // bf16 in high half
  return __builtin_bit_cast(float, v & 0xffff0000u);
}
__device__ __forceinline__ float tanh_fast(float x) {
  x = fminf(12.f, fmaxf(-12.f, x));
  float e = __expf(2.f * x);
  return __fdividef(e - 1.f, e + 1.f);
}

// ---------------------------------------------------------------------------
// Pre-pass: EK[v][u] = bf16( emb[v][:] @ k0[:][u] + b0[u] )   (V x 256, bf16)
// ---------------------------------------------------------------------------
__global__ __launch_bounds__(256) void ek_prepass(
    const float* __restrict__ emb, const float* __restrict__ k0,
    const float* __restrict__ b0, __hip_bfloat16* __restrict__ EK)
{
  __shared__ __align__(16) unsigned short k0t[256 * 136];
  const int tid = threadIdx.x;

  for (int it = 0; it < 32; ++it) {
    int e = it * 1024 + tid * 4;
    int k = e >> 8, c = e & 255;
    vfloat4 wv = *(const vfloat4*)(k0 + e);
    #pragma unroll
    for (int i = 0; i < 4; ++i) k0t[(c + i) * 136 + k] = f2bf(wv[i]);
  }
  __syncthreads();

  const int l = tid & 63, w = tid >> 6;
  const int lr = l & 15, q = l >> 4;

  bfrag8 Fb[4][4];
  #pragma unroll
  for (int ut = 0; ut < 4; ++ut) {
    #pragma unroll
    for (int kt = 0; kt < 4; ++kt) {
      int col = w * 64 + ut * 16 + lr;
      Fb[ut][kt] = *(const bfrag8*)((const char*)k0t + col * 272 + kt * 64 + q * 16);
    }
  }

  float b0v[4];
  #pragma unroll
  for (int ut = 0; ut < 4; ++ut) b0v[ut] = b0[w * 64 + ut * 16 + lr];

  const int v0 = blockIdx.x * 128;
  for (int mt = 0; mt < 8; ++mt) {
    int vr = v0 + mt * 16 + lr;
    int vc = vr < kV ? vr : kV - 1;
    bfrag8 Fa[4];
    #pragma unroll
    for (int kt = 0; kt < 4; ++kt) {
      const vfloat4* p = (const vfloat4*)(emb + vc * kD + kt * 32 + q * 8);
      vfloat4 x0 = p[0], x1 = p[1];
      bfrag8 a;
      #pragma unroll
      for (int i = 0; i < 4; ++i) {
        a[i]     = (short)f2bf(x0[i]);
        a[i + 4] = (short)f2bf(x1[i]);
      }
      Fa[kt] = a;
    }
    facc4 acc[4];
    #pragma unroll
    for (int ut = 0; ut < 4; ++ut) {
      facc4 ini = {b0v[ut], b0v[ut], b0v[ut], b0v[ut]};
      acc[ut] = ini;
    }
    #pragma unroll
    for (int kt = 0; kt < 4; ++kt) {
      #pragma unroll
      for (int ut = 0; ut < 4; ++ut)
        acc[ut] = __builtin_amdgcn_mfma_f32_16x16x32_bf16(Fa[kt], Fb[ut][kt], acc[ut], 0, 0, 0);
    }
    #pragma unroll
    for (int ut = 0; ut < 4; ++ut) {
      #pragma unroll
      for (int r = 0; r < 4; ++r) {
        int row = v0 + mt * 16 + q * 4 + r;
        if (row < kV)
          EK[row * kU + w * 64 + ut * 16 + lr] = __float2bfloat16(acc[ut][r]);
      }
    }
  }
}

// ---------------------------------------------------------------------------
// Persistent wave-specialized RNN: 32 blocks x 768 threads (12 waves).
// Waves 0-3  : layer0, wave w owns cols [64w, 64w+64)   (rk0 in regs, 128 VGPR)
// Waves 4-11 : layer1, wave w-4 owns cols [32(w-4), +32) (k1+rk1 in regs, 128)
// Pipeline: iteration i computes h0[i] (L0) and h1[i-1] (L1) concurrently.
// EK rows prefetched from global (L3-resident) one iteration ahead; indices
// two ahead. One __syncthreads per iteration.
// ---------------------------------------------------------------------------
__global__ __launch_bounds__(768, 1) void rnn_persist(
    const int* __restrict__ inputs, const __hip_bfloat16* __restrict__ EK,
    const float* __restrict__ rk0g, const float* __restrict__ k1g,
    const float* __restrict__ rk1g, const float* __restrict__ b1,
    const float* __restrict__ wo, const float* __restrict__ bo,
    float* __restrict__ out)
{
  __shared__ __align__(16) unsigned short h0s[2][16 * 256];  // swizzled bf16
  __shared__ __align__(16) unsigned short h1s[2][16 * 256];
  __shared__ __align__(16) unsigned short wT[256 * 72];      // staging [col][k]

  const int tid = threadIdx.x, blk = blockIdx.x;
  const int l = tid & 63, w = tid >> 6;
  const int lr = l & 15, q = l >> 4;
  const bool is0 = (w < 4);
  const int w1 = w - 4;
  const int sA = (lr & 7) << 4;                // A-fragment read swizzle (row=lr)
  const int cbase  = w * 64 + lr;              // layer0 col base
  const int c1base = w1 * 32 + lr;             // layer1 col base

  // ---- zero initial h state ----
  if (tid < 512) {
    bfrag8 z = {0, 0, 0, 0, 0, 0, 0, 0};
    *(bfrag8*)((char*)h0s[0] + tid * 16) = z;
    *(bfrag8*)((char*)h1s[0] + tid * 16) = z;
  }

  // ---- stage weights into per-wave register fragments ----
  bfrag8 Frk0[4][8], Fk1[2][8], Frk1[2][8];

  auto stage64 = [&](const float* __restrict__ SRC, int c) {
    __syncthreads();
    for (int it = 0; it < 6; ++it) {
      int e = it * 3072 + tid * 4;
      if (e < 16384) {
        int k = e >> 8, col = e & 255;
        vfloat4 wv = *(const vfloat4*)(SRC + (c * 64 + k) * 256 + col);
        #pragma unroll
        for (int i2 = 0; i2 < 4; ++i2) wT[(col + i2) * 72 + k] = f2bf(wv[i2]);
      }
    }
    __syncthreads();
  };

  for (int c = 0; c < 4; ++c) {
    stage64(rk0g, c);
    if (is0) {
      #pragma unroll
      for (int ut = 0; ut < 4; ++ut)
        #pragma unroll
        for (int kk = 0; kk < 2; ++kk)
          Frk0[ut][c * 2 + kk] = *(const bfrag8*)((const char*)wT +
              (cbase + ut * 16) * 144 + kk * 64 + q * 16);
    }
  }
  for (int c = 0; c < 4; ++c) {
    stage64(k1g, c);
    if (!is0) {
      #pragma unroll
      for (int ut = 0; ut < 2; ++ut)
        #pragma unroll
        for (int kk = 0; kk < 2; ++kk)
          Fk1[ut][c * 2 + kk] = *(const bfrag8*)((const char*)wT +
              (c1base + ut * 16) * 144 + kk * 64 + q * 16);
    }
  }
  for (int c = 0; c < 4; ++c) {
    stage64(rk1g, c);
    if (!is0) {
      #pragma unroll
      for (int ut = 0; ut < 2; ++ut)
        #pragma unroll
        for (int kk = 0; kk < 2; ++kk)
          Frk1[ut][c * 2 + kk] = *(const bfrag8*)((const char*)wT +
              (c1base + ut * 16) * 144 + kk * 64 + q * 16);
    }
  }

  float b1v[2] = {0.f, 0.f};
  if (!is0) {
    #pragma unroll
    for (int ut = 0; ut < 2; ++ut) b1v[ut] = b1[c1base + ut * 16];
  }

  // ---- layer0 prologue: EK[x_0] into regs, idx[1] into regs ----
  const unsigned short* __restrict__ EKu = (const unsigned short*)EK;
  const int rg0 = (blk * 16 + q * 4) * kT;     // row base; rows offset by r*kT
  unsigned ekp[8];                             // packed bf16 pairs (r even|odd<<16)
  int idxr[4];
  if (is0) {
    int i0[4];
    #pragma unroll
    for (int r = 0; r < 4; ++r) i0[r] = inputs[rg0 + r * kT];          // t=0
    #pragma unroll
    for (int ut = 0; ut < 4; ++ut) {
      #pragma unroll
      for (int p = 0; p < 2; ++p) {
        unsigned lo = EKu[(size_t)i0[2 * p]     * kU + cbase + ut * 16];
        unsigned hi = EKu[(size_t)i0[2 * p + 1] * kU + cbase + ut * 16];
        ekp[ut * 2 + p] = lo | (hi << 16);
      }
    }
    #pragma unroll
    for (int r = 0; r < 4; ++r) idxr[r] = inputs[rg0 + r * kT + 1];    // t=1
  }
  __syncthreads();

  // ---- pipelined main loop: 257 iterations, ONE barrier each ----
  for (int i = 0; i <= kT; ++i) {
    const int cur = i & 1, nxt = cur ^ 1;

    if (is0) {
      if (i < kT) {
        // h0[i] = tanh(EK[x_i] + h0[i-1] @ rk0); reads h0s[cur], writes h0s[nxt]
        facc4 acc[4];
        #pragma unroll
        for (int ut = 0; ut < 4; ++ut) {
          acc[ut][0] = bflo(ekp[ut * 2 + 0]);
          acc[ut][1] = bfhi(ekp[ut * 2 + 0]);
          acc[ut][2] = bflo(ekp[ut * 2 + 1]);
          acc[ut][3] = bfhi(ekp[ut * 2 + 1]);
        }
        // issue EK prefetch for t=i+1 (idxr holds idx at t=i+1)
        #pragma unroll
        for (int ut = 0; ut < 4; ++ut) {
          #pragma unroll
          for (int p = 0; p < 2; ++p) {
            unsigned lo = EKu[(size_t)idxr[2 * p]     * kU + cbase + ut * 16];
            unsigned hi = EKu[(size_t)idxr[2 * p + 1] * kU + cbase + ut * 16];
            ekp[ut * 2 + p] = lo | (hi << 16);
          }
        }
        // idx prefetch for t=i+2
        int tn = (i + 2 < kT) ? i + 2 : kT - 1;
        #pragma unroll
        for (int r = 0; r < 4; ++r) idxr[r] = inputs[rg0 + r * kT + tn];

        #pragma unroll
        for (int kt = 0; kt < 8; ++kt) {
          bfrag8 a = *(const bfrag8*)((const char*)h0s[cur] + lr * 512 + ((kt * 64 + q * 16) ^ sA));
          #pragma unroll
          for (int ut = 0; ut < 4; ++ut)
            acc[ut] = __builtin_amdgcn_mfma_f32_16x16x32_bf16(a, Frk0[ut][kt], acc[ut], 0, 0, 0);
        }
        #pragma unroll
        for (int ut = 0; ut < 4; ++ut) {
          #pragma unroll
          for (int r = 0; r < 4; ++r) {
            int rw = q * 4 + r;
            int byte = rw * 512 + ((((cbase + ut * 16) * 2)) ^ ((rw & 7) << 4));
            *(unsigned short*)((char*)h0s[nxt] + byte) = f2bf(tanh_fast(acc[ut][r]));
          }
        }
      }
    } else {
      if (i >= 1) {
        // h1[i-1] = tanh(b1 + h0[i-1] @ k1 + h1[i-2] @ rk1)
        // reads h0s[cur] (written last iter), h1s[nxt] (= (i-1)&1), writes h1s[cur]
        facc4 acc1[2];
        #pragma unroll
        for (int ut = 0; ut < 2; ++ut) {
          facc4 ini = {b1v[ut], b1v[ut], b1v[ut], b1v[ut]};
          acc1[ut] = ini;
        }
        #pragma unroll
        for (int kt = 0; kt < 8; ++kt) {
          int ro = (kt * 64 + q * 16) ^ sA;
          bfrag8 a0 = *(const bfrag8*)((const char*)h0s[cur] + lr * 512 + ro);
          bfrag8 a1 = *(const bfrag8*)((const char*)h1s[nxt] + lr * 512 + ro);
          #pragma unroll
          for (int ut = 0; ut < 2; ++ut) {
            acc1[ut] = __builtin_amdgcn_mfma_f32_16x16x32_bf16(a0, Fk1[ut][kt], acc1[ut], 0, 0, 0);
            acc1[ut] = __builtin_amdgcn_mfma_f32_16x16x32_bf16(a1, Frk1[ut][kt], acc1[ut], 0, 0, 0);
          }
        }
        #pragma unroll
        for (int ut = 0; ut < 2; ++ut) {
          #pragma unroll
          for (int r = 0; r < 4; ++r) {
            int rw = q * 4 + r;
            int byte = rw * 512 + ((((c1base + ut * 16) * 2)) ^ ((rw & 7) << 4));
            *(unsigned short*)((char*)h1s[cur] + byte) = f2bf(tanh_fast(acc1[ut][r]));
          }
        }
      }
    }
    __syncthreads();
  }

  // ---- epilogue: out = sigmoid(h1[T-1] @ wo + bo); h1[T-1] is in h1s[0] ----
  if (w == 0) {
    float dot = 0.f;
    #pragma unroll
    for (int c8 = 0; c8 < 8; ++c8) {
      int colb = (q * 64 + c8 * 8) * 2;
      bfrag8 hv = *(const bfrag8*)((const char*)h1s[0] + lr * 512 + (colb ^ sA));
      #pragma unroll
      for (int j = 0; j < 8; ++j)
        dot += bf2f((unsigned short)hv[j]) * wo[q * 64 + c8 * 8 + j];
    }
    dot += __shfl_xor(dot, 16);
    dot += __shfl_xor(dot, 32);
    if (l < 16) {
      float z = dot + bo[0];
      z = fminf(30.f, fmaxf(-30.f, z));
      out[blk * 16 + lr] = __fdividef(1.f, 1.f + __expf(-z));
    }
  }
}

}  // namespace

extern "C" void kernel_launch(void* const* d_in, const int* in_sizes, int n_in,
                              void* d_out, int out_size, void* d_ws, size_t ws_size,
                              hipStream_t stream) {
  const int*   inputs = (const int*)  d_in[0];
  const float* emb    = (const float*)d_in[1];
  const float* k0     = (const float*)d_in[2];
  const float* rk0    = (const float*)d_in[3];
  const float* b0     = (const float*)d_in[4];
  const float* k1     = (const float*)d_in[5];
  const float* rk1    = (const float*)d_in[6];
  const float* b1     = (const float*)d_in[7];
  const float* wo     = (const float*)d_in[8];
  const float* bo     = (const float*)d_in[9];
  float* out = (float*)d_out;

  __hip_bfloat16* EK = (__hip_bfloat16*)d_ws;          // V*U bf16 = 25.6 MB
  if (ws_size < (size_t)kV * kU * sizeof(__hip_bfloat16)) return;

  ek_prepass<<<(kV + 127) / 128, 256, 0, stream>>>(emb, k0, b0, EK);
  rnn_persist<<<kB / 16, 768, 0, stream>>>(inputs, EK, rk0, k1, rk1, b1, wo, bo, out);
}

// Round 3
// 822.703 us; speedup vs baseline: 2.6236x; 2.6236x over previous
//
#include <hip/hip_runtime.h>
#include <hip/hip_bf16.h>

namespace {

constexpr int kV = 50000;
constexpr int kD = 128;
constexpr int kB = 512;
constexpr int kT = 256;
constexpr int kU = 256;

typedef __attribute__((ext_vector_type(8))) short  bfrag8;   // 8 x bf16 -> 4 VGPR (MFMA operand)
typedef __attribute__((ext_vector_type(4))) float  facc4;    // MFMA accumulator
typedef __attribute__((ext_vector_type(4))) float  vfloat4;

__device__ __forceinline__ unsigned short f2bf(float f) {
  return __builtin_bit_cast(unsigned short, __float2bfloat16(f));
}
__device__ __forceinline__ float bf2f(unsigned short u) {
  unsigned int i = ((unsigned int)u) << 16;
  return __builtin_bit_cast(float, i);
}
__device__ __forceinline__ float bflo(unsigned v) {          // bf16 in low half
  return __builtin_bit_cast(float, v << 16);
}
__device__ __forceinline__ float bfhi(unsigned v) {          // bf16 in high half
  return __builtin_bit_cast(float, v & 0xffff0000u);
}
__device__ __forceinline__ float tanh_fast(float x) {
  float xc = fminf(10.f, fmaxf(-10.f, x));
  float e = __expf(2.f * xc);
  return 1.f - __fdividef(2.f, e + 1.f);
}
// LDS row swizzle: conflict-free for both b128 row-reads and scalar b16
// col-scatter writes (rows {r,4+r,8+r,12+r} land in disjoint bank octets).
__device__ __forceinline__ int swz(int row) {
  return ((row & 7) << 4) ^ ((row & 8) << 2);
}

// ---------------------------------------------------------------------------
// Pre-pass: EK[v][u] = bf16( emb[v][:] @ k0[:][u] + b0[u] )   (V x 256, bf16)
// ---------------------------------------------------------------------------
__global__ __launch_bounds__(256) void ek_prepass(
    const float* __restrict__ emb, const float* __restrict__ k0,
    const float* __restrict__ b0, __hip_bfloat16* __restrict__ EK)
{
  __shared__ __align__(16) unsigned short k0t[256 * 136];
  const int tid = threadIdx.x;

  for (int it = 0; it < 32; ++it) {
    int e = it * 1024 + tid * 4;
    int k = e >> 8, c = e & 255;
    vfloat4 wv = *(const vfloat4*)(k0 + e);
    #pragma unroll
    for (int i = 0; i < 4; ++i) k0t[(c + i) * 136 + k] = f2bf(wv[i]);
  }
  __syncthreads();

  const int l = tid & 63, w = tid >> 6;
  const int lr = l & 15, q = l >> 4;

  bfrag8 Fb[4][4];
  #pragma unroll
  for (int ut = 0; ut < 4; ++ut) {
    #pragma unroll
    for (int kt = 0; kt < 4; ++kt) {
      int col = w * 64 + ut * 16 + lr;
      Fb[ut][kt] = *(const bfrag8*)((const char*)k0t + col * 272 + kt * 64 + q * 16);
    }
  }

  float b0v[4];
  #pragma unroll
  for (int ut = 0; ut < 4; ++ut) b0v[ut] = b0[w * 64 + ut * 16 + lr];

  const int v0 = blockIdx.x * 128;
  for (int mt = 0; mt < 8; ++mt) {
    int vr = v0 + mt * 16 + lr;
    int vc = vr < kV ? vr : kV - 1;
    bfrag8 Fa[4];
    #pragma unroll
    for (int kt = 0; kt < 4; ++kt) {
      const vfloat4* p = (const vfloat4*)(emb + vc * kD + kt * 32 + q * 8);
      vfloat4 x0 = p[0], x1 = p[1];
      bfrag8 a;
      #pragma unroll
      for (int i = 0; i < 4; ++i) {
        a[i]     = (short)f2bf(x0[i]);
        a[i + 4] = (short)f2bf(x1[i]);
      }
      Fa[kt] = a;
    }
    facc4 acc[4];
    #pragma unroll
    for (int ut = 0; ut < 4; ++ut) {
      facc4 ini = {b0v[ut], b0v[ut], b0v[ut], b0v[ut]};
      acc[ut] = ini;
    }
    #pragma unroll
    for (int kt = 0; kt < 4; ++kt) {
      #pragma unroll
      for (int ut = 0; ut < 4; ++ut)
        acc[ut] = __builtin_amdgcn_mfma_f32_16x16x32_bf16(Fa[kt], Fb[ut][kt], acc[ut], 0, 0, 0);
    }
    #pragma unroll
    for (int ut = 0; ut < 4; ++ut) {
      #pragma unroll
      for (int r = 0; r < 4; ++r) {
        int row = v0 + mt * 16 + q * 4 + r;
        if (row < kV)
          EK[row * kU + w * 64 + ut * 16 + lr] = __float2bfloat16(acc[ut][r]);
      }
    }
  }
}

// ---------------------------------------------------------------------------
// Persistent RNN: 32 blocks x 512 threads (8 waves, 2 waves/SIMD).
// Wave w owns output cols [32w, 32w+32) of BOTH layers; weights in registers
// (3 x [2][8] bfrag8 = 192 VGPR). Double-buffered swizzled LDS h-state, ONE
// __syncthreads per step (GEMM1(t) of slow waves overlaps GEMM0(t+1) of fast
// waves safely). EK rows register-prefetched 1 step ahead, indices 2 ahead.
// ---------------------------------------------------------------------------
__global__ __launch_bounds__(512, 2) void rnn_persist(
    const int* __restrict__ inputs, const __hip_bfloat16* __restrict__ EK,
    const float* __restrict__ rk0g, const float* __restrict__ k1g,
    const float* __restrict__ rk1g, const float* __restrict__ b1,
    const float* __restrict__ wo, const float* __restrict__ bo,
    float* __restrict__ out)
{
  __shared__ __align__(16) unsigned short h0s[2][16 * 256];  // swizzled bf16
  __shared__ __align__(16) unsigned short h1s[2][16 * 256];
  __shared__ __align__(16) unsigned short wT[256 * 72];      // staging [col][k]

  const int tid = threadIdx.x, blk = blockIdx.x;
  const int l = tid & 63, w = tid >> 6;
  const int lr = l & 15, q = l >> 4;
  const int cbase = w * 32 + lr;               // this wave's col base (+ut*16)
  const int sR = swz(lr);                      // A-fragment read swizzle (row=lr)

  // ---- zero initial h state (buffers [0]) ----
  {
    bfrag8 z = {0, 0, 0, 0, 0, 0, 0, 0};
    *(bfrag8*)((char*)h0s[0] + tid * 16) = z;
    *(bfrag8*)((char*)h1s[0] + tid * 16) = z;
  }

  // ---- stage weights into per-wave register fragments (ALL loops unrolled:
  //      runtime-indexed ext_vector arrays would go to scratch) ----
  bfrag8 Frk0[2][8], Fk1[2][8], Frk1[2][8];

#define STAGE_MAT(SRC, DST)                                                    \
  _Pragma("unroll")                                                            \
  for (int c = 0; c < 4; ++c) {                                                \
    __syncthreads();                                                           \
    for (int it = 0; it < 8; ++it) {                                           \
      int e = it * 2048 + tid * 4;                                             \
      int k = e >> 8, col = e & 255;                                           \
      vfloat4 wv = *(const vfloat4*)(SRC + (c * 64 + k) * 256 + col);          \
      _Pragma("unroll")                                                        \
      for (int i2 = 0; i2 < 4; ++i2) wT[(col + i2) * 72 + k] = f2bf(wv[i2]);   \
    }                                                                          \
    __syncthreads();                                                           \
    _Pragma("unroll")                                                          \
    for (int ut = 0; ut < 2; ++ut) {                                           \
      _Pragma("unroll")                                                        \
      for (int kk = 0; kk < 2; ++kk)                                           \
        DST[ut][c * 2 + kk] = *(const bfrag8*)((const char*)wT +               \
            (cbase + ut * 16) * 144 + kk * 64 + q * 16);                       \
    }                                                                          \
  }

  STAGE_MAT(rk0g, Frk0);
  STAGE_MAT(k1g, Fk1);
  STAGE_MAT(rk1g, Frk1);
#undef STAGE_MAT

  float b1v[2];
  #pragma unroll
  for (int ut = 0; ut < 2; ++ut) b1v[ut] = b1[cbase + ut * 16];

  // ---- EK/idx register prefetch pipeline ----
  const unsigned short* __restrict__ EKu = (const unsigned short*)EK;
  const int rg0 = (blk * 16 + q * 4) * kT;     // rows rg0 + r*kT, r=0..3
  unsigned ekp[4];                             // [ut][p]: rows (q*4+2p, +1) packed
  int idxr[4];
  {
    int i0[4];
    #pragma unroll
    for (int r = 0; r < 4; ++r) i0[r] = inputs[rg0 + r * kT];          // t=0
    #pragma unroll
    for (int ut = 0; ut < 2; ++ut) {
      #pragma unroll
      for (int p = 0; p < 2; ++p) {
        unsigned lo = EKu[((unsigned)i0[2 * p]     << 8) + cbase + ut * 16];
        unsigned hi = EKu[((unsigned)i0[2 * p + 1] << 8) + cbase + ut * 16];
        ekp[ut * 2 + p] = lo | (hi << 16);
      }
    }
    #pragma unroll
    for (int r = 0; r < 4; ++r) idxr[r] = inputs[rg0 + r * kT + 1];    // t=1
  }
  __syncthreads();

  // ---- main loop: ONE barrier per step ----
  for (int t = 0; t < kT; ++t) {
    const int cur = t & 1, nxt = cur ^ 1;
    const char* h0c = (const char*)h0s[cur];
    char*       h0n = (char*)h0s[nxt];
    const char* h1c = (const char*)h1s[cur];
    char*       h1n = (char*)h1s[nxt];

    // ---- GEMM0: h0' = tanh(EK[x_t] + h0 @ rk0) ----
    facc4 acc[2];
    #pragma unroll
    for (int ut = 0; ut < 2; ++ut) {
      acc[ut][0] = bflo(ekp[ut * 2 + 0]);
      acc[ut][1] = bfhi(ekp[ut * 2 + 0]);
      acc[ut][2] = bflo(ekp[ut * 2 + 1]);
      acc[ut][3] = bfhi(ekp[ut * 2 + 1]);
    }
    // issue EK gather for t+1 (idxr holds idx at t+1); lands next iteration
    #pragma unroll
    for (int ut = 0; ut < 2; ++ut) {
      #pragma unroll
      for (int p = 0; p < 2; ++p) {
        unsigned lo = EKu[((unsigned)idxr[2 * p]     << 8) + cbase + ut * 16];
        unsigned hi = EKu[((unsigned)idxr[2 * p + 1] << 8) + cbase + ut * 16];
        ekp[ut * 2 + p] = lo | (hi << 16);
      }
    }
    {  // idx prefetch for t+2
      int tn = (t + 2 < kT) ? t + 2 : kT - 1;
      #pragma unroll
      for (int r = 0; r < 4; ++r) idxr[r] = inputs[rg0 + r * kT + tn];
    }

    #pragma unroll
    for (int kt = 0; kt < 8; ++kt) {
      bfrag8 a = *(const bfrag8*)(h0c + lr * 512 + ((kt * 64 + q * 16) ^ sR));
      #pragma unroll
      for (int ut = 0; ut < 2; ++ut)
        acc[ut] = __builtin_amdgcn_mfma_f32_16x16x32_bf16(a, Frk0[ut][kt], acc[ut], 0, 0, 0);
    }
    #pragma unroll
    for (int ut = 0; ut < 2; ++ut) {
      #pragma unroll
      for (int r = 0; r < 4; ++r) {
        int rw = q * 4 + r;
        int byte = rw * 512 + ((((cbase + ut * 16) * 2)) ^ swz(rw));
        *(unsigned short*)(h0n + byte) = f2bf(tanh_fast(acc[ut][r]));
      }
    }

    __syncthreads();   // the single per-step barrier

    // ---- GEMM1: h1' = tanh(b1 + h0' @ k1 + h1 @ rk1) ----
    facc4 accA[2], accB[2];                    // split accs: 4-way MFMA ILP
    #pragma unroll
    for (int ut = 0; ut < 2; ++ut) {
      facc4 ini = {b1v[ut], b1v[ut], b1v[ut], b1v[ut]};
      accA[ut] = ini;
      facc4 zz = {0.f, 0.f, 0.f, 0.f};
      accB[ut] = zz;
    }
    #pragma unroll
    for (int kt = 0; kt < 8; ++kt) {
      int ro = (kt * 64 + q * 16) ^ sR;
      bfrag8 a0 = *(const bfrag8*)(h0n + lr * 512 + ro);
      bfrag8 a1 = *(const bfrag8*)(h1c + lr * 512 + ro);
      #pragma unroll
      for (int ut = 0; ut < 2; ++ut) {
        accA[ut] = __builtin_amdgcn_mfma_f32_16x16x32_bf16(a0, Fk1[ut][kt], accA[ut], 0, 0, 0);
        accB[ut] = __builtin_amdgcn_mfma_f32_16x16x32_bf16(a1, Frk1[ut][kt], accB[ut], 0, 0, 0);
      }
    }
    #pragma unroll
    for (int ut = 0; ut < 2; ++ut) {
      #pragma unroll
      for (int r = 0; r < 4; ++r) {
        int rw = q * 4 + r;
        int byte = rw * 512 + ((((cbase + ut * 16) * 2)) ^ swz(rw));
        *(unsigned short*)(h1n + byte) = f2bf(tanh_fast(accA[ut][r] + accB[ut][r]));
      }
    }
  }
  __syncthreads();

  // ---- epilogue: out = sigmoid(h1[T-1] @ wo + bo); h1[T-1] is in h1s[0] ----
  if (w == 0) {
    float dot = 0.f;
    #pragma unroll
    for (int c8 = 0; c8 < 8; ++c8) {
      int colb = (q * 64 + c8 * 8) * 2;
      bfrag8 hv = *(const bfrag8*)((const char*)h1s[0] + lr * 512 + (colb ^ sR));
      #pragma unroll
      for (int j = 0; j < 8; ++j)
        dot += bf2f((unsigned short)hv[j]) * wo[q * 64 + c8 * 8 + j];
    }
    dot += __shfl_xor(dot, 16);
    dot += __shfl_xor(dot, 32);
    if (l < 16) {
      float z = dot + bo[0];
      z = fminf(30.f, fmaxf(-30.f, z));
      out[blk * 16 + lr] = __fdividef(1.f, 1.f + __expf(-z));
    }
  }
}

}  // namespace

extern "C" void kernel_launch(void* const* d_in, const int* in_sizes, int n_in,
                              void* d_out, int out_size, void* d_ws, size_t ws_size,
                              hipStream_t stream) {
  const int*   inputs = (const int*)  d_in[0];
  const float* emb    = (const float*)d_in[1];
  const float* k0     = (const float*)d_in[2];
  const float* rk0    = (const float*)d_in[3];
  const float* b0     = (const float*)d_in[4];
  const float* k1     = (const float*)d_in[5];
  const float* rk1    = (const float*)d_in[6];
  const float* b1     = (const float*)d_in[7];
  const float* wo     = (const float*)d_in[8];
  const float* bo     = (const float*)d_in[9];
  float* out = (float*)d_out;

  __hip_bfloat16* EK = (__hip_bfloat16*)d_ws;          // V*U bf16 = 25.6 MB
  if (ws_size < (size_t)kV * kU * sizeof(__hip_bfloat16)) return;

  ek_prepass<<<(kV + 127) / 128, 256, 0, stream>>>(emb, k0, b0, EK);
  rnn_persist<<<kB / 16, 512, 0, stream>>>(inputs, EK, rk0, k1, rk1, b1, wo, bo, out);
}